// Round 11
// baseline (1228.787 us; speedup 1.0000x reference)
//
#include <hip/hip_runtime.h>
#include <hip/hip_bf16.h>

// Round 11: consolidation on the round-10 winner (one barrier/step, counted vmcnt).
//  1) Triple-unrolled ring main loop: cb/sb are compile-time constants -> LDS read
//     offsets fold into ds_read imm fields, ring VALU disappears (VALUBusy 24%->~18).
//     Generic 5-step tail reproduces the exact round-10 pf/drain ledger.
//  2) Stage-first ordering inside each step (T3 recipe: issue loads before reads+MFMA).
//  3) conv_wd2 both experts in one launch.
// Sync structure per step IDENTICAL to round 10 (stage 4 loads, [reads, MFMA],
// vmcnt(4) -> barrier; tail vmcnt(0) at N-2, nothing at N-1).

#define HDIM 4096
#define IDIM 11008
#define N2   22016
#define MTOK 2048
#define KT1  64      // HDIM/64
#define KT2  172     // IDIM/64
#define NB1  86      // IDIM/128
#define NB2  32      // HDIM/128
#define NKD  344     // 2*KT2: down K-steps of 32
#define NPG  128     // 2*KT1: gu K-steps of 32

typedef unsigned short ushort_t;
using f32x4  = __attribute__((ext_vector_type(4))) float;
using bf16x8 = __attribute__((ext_vector_type(8))) short;
using u32x2  = __attribute__((ext_vector_type(2))) unsigned int;
using u32x4  = __attribute__((ext_vector_type(4))) unsigned int;

__device__ __forceinline__ unsigned int bf16rne(float f) {
    unsigned int u = __builtin_bit_cast(unsigned int, f);
    return (u + 0x7FFFu + ((u >> 16) & 1u)) >> 16;
}
__device__ __forceinline__ unsigned int pack2(float lo, float hi) {
    return bf16rne(lo) | (bf16rne(hi) << 16);
}
__device__ __forceinline__ void gl_lds16(const void* g, void* l) {
    __builtin_amdgcn_global_load_lds(
        (const __attribute__((address_space(1))) void*)g,
        (__attribute__((address_space(3))) void*)l, 16, 0, 0);
}

// ---------------- conversion kernels (fp32 -> packed bf16 units, proven) ----------------

__global__ __launch_bounds__(256)
void conv_x(const float* __restrict__ X, ushort_t* __restrict__ XP) {
    int bid = blockIdx.x;               // 16 mb128 * 64 kt
    int mb = bid >> 6, kt = bid & 63;
    int t = threadIdx.x;
    int r0 = t >> 4, c4 = t & 15;
    int kh = c4 >> 3, c = (c4 >> 1) & 3, lo4 = (c4 & 1) << 2;
    ushort_t* tp = XP + ((long)(mb >> 1) * KT1 + kt) * 16384 + (long)kh * 8192 + (mb & 1) * 4096;
#pragma unroll
    for (int p = 0; p < 8; ++p) {
        int rl = r0 + p * 16;
        f32x4 v = *(const f32x4*)(X + (long)(mb * 128 + rl) * HDIM + kt * 64 + c4 * 4);
        u32x2 pk = { pack2(v[0], v[1]), pack2(v[2], v[3]) };
        int q = rl >> 1;
        int pos = ((((rl & 1) << 2) | c) ^ (q & 7));
        *(u32x2*)&tp[q * 64 + pos * 8 + lo4] = pk;
    }
}

__global__ __launch_bounds__(256)
void conv_wgu(const float* __restrict__ W, ushort_t* __restrict__ WP) {
    int bid = blockIdx.x;               // nb(86)*kt(64)*e(2)
    int e = bid & 1, kt = (bid >> 1) & 63, nb = bid >> 7;
    int t = threadIdx.x;
    int kp = t >> 5, c4 = t & 31;
    const float* p = W + ((long)kt * 64 + kp * 8) * N2 + (long)e * IDIM + nb * 128 + c4 * 4;
    f32x4 v[8];
#pragma unroll
    for (int j = 0; j < 8; ++j) v[j] = *(const f32x4*)(p + (long)j * N2);
    ushort_t* tp = WP + ((long)nb * KT1 + kt) * 16384 + (long)(kp >> 2) * 8192 + e * 4096;
    int c = kp & 3;
#pragma unroll
    for (int cc = 0; cc < 4; ++cc) {
        int n = c4 * 4 + cc;
        int q = n >> 1;
        int pos = ((((n & 1) << 2) | c) ^ (q & 7));
        u32x4 pk = { pack2(v[0][cc], v[1][cc]), pack2(v[2][cc], v[3][cc]),
                     pack2(v[4][cc], v[5][cc]), pack2(v[6][cc], v[7][cc]) };
        *(u32x4*)&tp[q * 64 + pos * 8] = pk;
    }
}

// both experts in one launch: bid -> e(0/1), nb(0..15), kt
__global__ __launch_bounds__(256)
void conv_wd2b(const float* __restrict__ Wl, const float* __restrict__ Wv,
               ushort_t* __restrict__ WPd) {
    int bid = blockIdx.x;               // 32*KT2
    int kt = bid % KT2, nbp = bid / KT2;
    int e = nbp >> 4, nb = nbp & 15;
    const float* W = e ? Wv : Wl;
    int t = threadIdx.x;
    int kp = t >> 5, c4 = t & 31;
    ushort_t* tp = WPd + ((long)nbp * KT2 + kt) * 16384 + (long)(kp >> 2) * 8192;
    int c = kp & 3;
#pragma unroll
    for (int h = 0; h < 2; ++h) {
        const float* p = W + ((long)kt * 64 + kp * 8) * HDIM + nb * 256 + h * 128 + c4 * 4;
        f32x4 v[8];
#pragma unroll
        for (int j = 0; j < 8; ++j) v[j] = *(const f32x4*)(p + (long)j * HDIM);
#pragma unroll
        for (int cc = 0; cc < 4; ++cc) {
            int n = h * 128 + c4 * 4 + cc;
            int q = n >> 1;
            int pos = ((((n & 1) << 2) | c) ^ (q & 7));
            u32x4 pk = { pack2(v[0][cc], v[1][cc]), pack2(v[2][cc], v[3][cc]),
                         pack2(v[4][cc], v[5][cc]), pack2(v[6][cc], v[7][cc]) };
            *(u32x4*)&tp[q * 64 + pos * 8] = pk;
        }
    }
}

__global__ __launch_bounds__(256)
void conv_wd(const float* __restrict__ W, ushort_t* __restrict__ WP) {
    int bid = blockIdx.x;               // nb(32)*kt(172)
    int kt = bid % KT2, nb = bid / KT2;
    int t = threadIdx.x;
    int kp = t >> 5, c4 = t & 31;
    const float* p = W + ((long)kt * 64 + kp * 8) * HDIM + nb * 128 + c4 * 4;
    f32x4 v[8];
#pragma unroll
    for (int j = 0; j < 8; ++j) v[j] = *(const f32x4*)(p + (long)j * HDIM);
    ushort_t* tp = WP + ((long)nb * KT2 + kt) * 8192 + (long)(kp >> 2) * 4096;
    int c = kp & 3;
#pragma unroll
    for (int cc = 0; cc < 4; ++cc) {
        int n = c4 * 4 + cc;
        int q = n >> 1;
        int pos = ((((n & 1) << 2) | c) ^ (q & 7));
        u32x4 pk = { pack2(v[0][cc], v[1][cc]), pack2(v[2][cc], v[3][cc]),
                     pack2(v[4][cc], v[5][cc]), pack2(v[6][cc], v[7][cc]) };
        *(u32x4*)&tp[q * 64 + pos * 8] = pk;
    }
}

// stage one 16KB unit (8192 shorts): 2 x global_load_lds per thread, linear dest
#define STAGE_U(SRC, DSTOFF) do { \
    gl_lds16((SRC) + so + lane * 8, &lds[(DSTOFF) + so]); \
    gl_lds16((SRC) + 4096 + so + lane * 8, &lds[(DSTOFF) + 4096 + so]); } while (0)

#define MFMA16(ACC, AF, BF) \
    _Pragma("unroll") \
    for (int mf = 0; mf < 4; ++mf) \
        _Pragma("unroll") \
        for (int nf = 0; nf < 4; ++nf) \
            ACC[mf][nf] = __builtin_amdgcn_mfma_f32_16x16x32_bf16(AF[mf], BF[nf], ACC[mf][nf], 0, 0, 0);

#define VMCNT_MID(N) do { \
    if (pf) asm volatile("s_waitcnt vmcnt(" #N ")" ::: "memory"); \
    else    asm volatile("s_waitcnt vmcnt(0)" ::: "memory"); } while (0)
#define VMCNT_END(N) do { \
    if (pf) asm volatile("s_waitcnt vmcnt(" #N ")" ::: "memory"); } while (0)

// ---------------- GEMM1: gate/up + silu, ring-3, const-folded main loop ----------------
// step body: stage(kt+2 -> SB) | reads(CB) | setprio+32 MFMA | vmcnt | barrier
#define GU_BODY(KT, CB, SB, PF) do { \
    if (PF) { STAGE_U(srcA + (long)((KT) + 2) * 8192, (SB)); \
              STAGE_U(srcB + (long)((KT) + 2) * 8192, (SB) + 8192); } \
    bf16x8 af[4], bg[4], bu[4]; \
    _Pragma("unroll") for (int mf = 0; mf < 4; ++mf) af[mf] = *(const bf16x8*)&lds[(CB) + aoff[mf]]; \
    _Pragma("unroll") for (int nf = 0; nf < 4; ++nf) { \
        bg[nf] = *(const bf16x8*)&lds[(CB) + 8192 + boff[nf]]; \
        bu[nf] = *(const bf16x8*)&lds[(CB) + 12288 + boff[nf]]; } \
    __builtin_amdgcn_s_setprio(1); \
    MFMA16(accg, af, bg); \
    MFMA16(accu, af, bu); \
    __builtin_amdgcn_s_setprio(0); \
    if (PF)                  asm volatile("s_waitcnt vmcnt(4)" ::: "memory"); \
    else if ((KT) + 1 < NPG) asm volatile("s_waitcnt vmcnt(0)" ::: "memory"); \
    __builtin_amdgcn_s_barrier(); \
} while (0)

__global__ __launch_bounds__(512, 2)
void gu14_kernel(const ushort_t* __restrict__ XP, const ushort_t* __restrict__ WP,
                 ushort_t* __restrict__ HP) {
    __shared__ ushort_t lds[49152];     // ring-3 x [A-unit 8192sh | B-unit(g|u) 8192sh]
    int nwg = gridDim.x;                // 688
    int cpx = nwg >> 3;
    int sw  = (blockIdx.x & 7) * cpx + (blockIdx.x >> 3);
    int mblk = sw & 7;                  // 0..7
    int nblk = sw >> 3;                 // 0..85
    const int t = threadIdx.x, lane = t & 63, w = t >> 6;
    const int wr = w >> 1, wc = w & 1;  // 4M x 2N waves
    const int rr = lane & 15, g4 = lane >> 4;
    const int so = w * 512;

    int aoff[4], boff[4];
#pragma unroll
    for (int mf = 0; mf < 4; ++mf) {
        int m = wr * 64 + mf * 16 + rr, q = m >> 1;
        aoff[mf] = q * 64 + ((((((m & 1) << 2) | g4) ^ (q & 7))) << 3);
    }
#pragma unroll
    for (int nf = 0; nf < 4; ++nf) {
        int n = wc * 64 + nf * 16 + rr, q = n >> 1;
        boff[nf] = q * 64 + ((((((n & 1) << 2) | g4) ^ (q & 7))) << 3);
    }

    f32x4 accg[4][4] = {}, accu[4][4] = {};
    const ushort_t* srcA = XP + (long)mblk * KT1 * 16384;
    const ushort_t* srcB = WP + (long)nblk * KT1 * 16384;

    // prologue: stage unit 0 -> slot0, unit 1 -> slot1
    STAGE_U(srcA, 0);
    STAGE_U(srcB, 8192);
    STAGE_U(srcA + 8192, 16384);
    STAGE_U(srcB + 8192, 16384 + 8192);
    asm volatile("s_waitcnt vmcnt(4)" ::: "memory");   // unit 0 landed
    __builtin_amdgcn_s_barrier();

    // main loop: cb/sb compile-time constants (slot = kt%3; stage slot = (kt+2)%3)
    int kt = 0;
    for (; kt + 5 < NPG; kt += 3) {
        GU_BODY(kt + 0, 0,     32768, true);
        GU_BODY(kt + 1, 16384, 0,     true);
        GU_BODY(kt + 2, 32768, 16384, true);
    }
    // generic tail (5 steps), exact round-10 ledger
    int cbv = (kt % 3) * 16384;
    for (; kt < NPG; ++kt) {
        int sbv = cbv + 32768; if (sbv >= 49152) sbv -= 49152;
        GU_BODY(kt, cbv, sbv, (kt + 2 < NPG));
        cbv += 16384; if (cbv == 49152) cbv = 0;
    }

    // epilogue: silu(g)*u -> HP packed tiles
#pragma unroll
    for (int nf = 0; nf < 4; ++nf) {
        int nloc = wc * 64 + nf * 16 + rr;
        int kt2 = nblk * 2 + (nloc >> 6);
        int k = nloc & 63;
        int kh = k >> 5, c = (k >> 3) & 3, klow = k & 7;
        ushort_t* tp = HP + ((long)mblk * KT2 + kt2) * 16384 + kh * 8192 + klow;
#pragma unroll
        for (int mf = 0; mf < 4; ++mf)
#pragma unroll
            for (int i = 0; i < 4; ++i) {
                int m = wr * 64 + mf * 16 + g4 * 4 + i;
                int q = m >> 1;
                int pos = ((((m & 1) << 2) | c) ^ (q & 7));
                float gv = accg[mf][nf][i], uv = accu[mf][nf][i];
                float s = gv / (1.0f + __expf(-gv));
                tp[q * 64 + pos * 8] = (ushort_t)bf16rne(s * uv);
            }
    }
}

// ---------------- GEMM2 tier-1: both experts, 256x256, ring-3, const-folded ----------------
#define DOWN_BODY(KT, CB, SB, PF) do { \
    if (PF) { STAGE_U(srcA + (long)((KT) + 2) * 8192, (SB)); \
              STAGE_U(srcB + (long)((KT) + 2) * 8192, (SB) + 8192); } \
    bf16x8 af[8], bf[4]; \
    _Pragma("unroll") for (int mf = 0; mf < 8; ++mf) af[mf] = *(const bf16x8*)&lds[(CB) + aoff[mf]]; \
    _Pragma("unroll") for (int nf = 0; nf < 4; ++nf) bf[nf] = *(const bf16x8*)&lds[(CB) + 8192 + boff[nf]]; \
    __builtin_amdgcn_s_setprio(1); \
    _Pragma("unroll") for (int mf = 0; mf < 8; ++mf) \
        _Pragma("unroll") for (int nf = 0; nf < 4; ++nf) \
            acc[mf][nf] = __builtin_amdgcn_mfma_f32_16x16x32_bf16(af[mf], bf[nf], acc[mf][nf], 0, 0, 0); \
    __builtin_amdgcn_s_setprio(0); \
    if (PF)                  asm volatile("s_waitcnt vmcnt(4)" ::: "memory"); \
    else if ((KT) + 1 < NKD) asm volatile("s_waitcnt vmcnt(0)" ::: "memory"); \
    __builtin_amdgcn_s_barrier(); \
} while (0)

__global__ __launch_bounds__(512, 2)
void down7_kernel(const ushort_t* __restrict__ HP, const ushort_t* __restrict__ WPd,
                  float* __restrict__ Out) {
    __shared__ ushort_t lds[49152];     // ring-3 x [A-unit 8192 | B-unit 8192]
    int nwg = gridDim.x;                // 256
    int cpx = nwg >> 3;
    int sw  = (blockIdx.x & 7) * cpx + (blockIdx.x >> 3);
    int mblk = sw & 15;                 // 0..15 (expert = mblk>>3)
    int nblk = sw >> 4;                 // 0..15
    const int t = threadIdx.x, lane = t & 63, w = t >> 6;
    const int wr = w >> 2, wc = w & 3;  // 2M x 4N waves, per-wave out 128x64
    const int rr = lane & 15, g4 = lane >> 4;
    const int so = w * 512;

    int aoff[8], boff[4];
#pragma unroll
    for (int mf = 0; mf < 8; ++mf) {
        int m = wr * 128 + mf * 16 + rr, q = m >> 1;
        aoff[mf] = q * 64 + ((((((m & 1) << 2) | g4) ^ (q & 7))) << 3);
    }
#pragma unroll
    for (int nf = 0; nf < 4; ++nf) {
        int n = wc * 64 + nf * 16 + rr, q = n >> 1;
        boff[nf] = q * 64 + ((((((n & 1) << 2) | g4) ^ (q & 7))) << 3);
    }

    f32x4 acc[8][4] = {};
    const ushort_t* srcA = HP  + (long)mblk * KT2 * 16384;
    const ushort_t* srcB = WPd + (long)(((mblk >> 3) << 4) + nblk) * KT2 * 16384;

    STAGE_U(srcA, 0);
    STAGE_U(srcB, 8192);
    STAGE_U(srcA + 8192, 16384);
    STAGE_U(srcB + 8192, 16384 + 8192);
    asm volatile("s_waitcnt vmcnt(4)" ::: "memory");
    __builtin_amdgcn_s_barrier();

    int kt = 0;
    for (; kt + 5 < NKD; kt += 3) {
        DOWN_BODY(kt + 0, 0,     32768, true);
        DOWN_BODY(kt + 1, 16384, 0,     true);
        DOWN_BODY(kt + 2, 32768, 16384, true);
    }
    int cbv = (kt % 3) * 16384;
    for (; kt < NKD; ++kt) {
        int sbv = cbv + 32768; if (sbv >= 49152) sbv -= 49152;
        DOWN_BODY(kt, cbv, sbv, (kt + 2 < NKD));
        cbv += 16384; if (cbv == 49152) cbv = 0;
    }

#pragma unroll
    for (int mf = 0; mf < 8; ++mf)
#pragma unroll
        for (int nf = 0; nf < 4; ++nf)
#pragma unroll
            for (int i = 0; i < 4; ++i) {
                int m = mblk * 256 + wr * 128 + mf * 16 + g4 * 4 + i;
                int n = nblk * 256 + wc * 64 + nf * 16 + rr;
                Out[(long)m * HDIM + n] = acc[mf][nf][i];
            }
}

// ---------------- GEMM2 tier-2: per-expert 256x128 (round-4, proven) ----------------
__global__ __launch_bounds__(512, 2)
void down3_kernel(const ushort_t* __restrict__ HP, const ushort_t* __restrict__ WP,
                  float* __restrict__ Out) {
    __shared__ ushort_t lds[49152];
    int nwg = gridDim.x;
    int cpx = nwg >> 3;
    int sw  = (blockIdx.x & 7) * cpx + (blockIdx.x >> 3);
    int mblk = sw & 7;
    int nblk = sw >> 3;
    const int t = threadIdx.x, lane = t & 63, w = t >> 6;
    const int wr = w >> 1, wc = w & 1;
    const int rr = lane & 15, g4 = lane >> 4;
    const int so = w * 512;

    int aoff[4], boff[4];
#pragma unroll
    for (int mf = 0; mf < 4; ++mf) {
        int m = wr * 64 + mf * 16 + rr, q = m >> 1;
        aoff[mf] = q * 64 + ((((((m & 1) << 2) | g4) ^ (q & 7))) << 3);
    }
#pragma unroll
    for (int nf = 0; nf < 4; ++nf) {
        int n = wc * 64 + nf * 16 + rr, q = n >> 1;
        boff[nf] = q * 64 + ((((((n & 1) << 2) | g4) ^ (q & 7))) << 3);
    }

    f32x4 acc[4][4] = {};
    const ushort_t* srcA = HP + (long)mblk * KT2 * 16384;
    const ushort_t* srcB = WP + (long)nblk * KT2 * 8192;

    STAGE_U(srcA, 0);
    STAGE_U(srcA + 8192, 8192);
    STAGE_U(srcB, 16384);
    asm volatile("s_waitcnt vmcnt(0)" ::: "memory");
    __builtin_amdgcn_s_barrier();

    int cur = 0;
    for (int kt = 0; kt < KT2; ++kt) {
        const int cb = cur * 24576, pb = (cur ^ 1) * 24576;
        const ushort_t* nA = srcA + (long)(kt + 1) * 16384;
        const ushort_t* nB = srcB + (long)(kt + 1) * 8192;
        const bool pf = (kt + 1 < KT2);
        bf16x8 af[4], bfr[4];

#pragma unroll
        for (int mf = 0; mf < 4; ++mf) af[mf] = *(const bf16x8*)&lds[cb + aoff[mf]];
#pragma unroll
        for (int nf = 0; nf < 4; ++nf) bfr[nf] = *(const bf16x8*)&lds[cb + 16384 + boff[nf]];
        if (pf) { STAGE_U(nA, pb); STAGE_U(nB, pb + 16384); }
        __builtin_amdgcn_s_barrier();
        __builtin_amdgcn_s_setprio(1);
        MFMA16(acc, af, bfr);
        __builtin_amdgcn_s_setprio(0);
        VMCNT_MID(4);
        __builtin_amdgcn_s_barrier();

#pragma unroll
        for (int mf = 0; mf < 4; ++mf) af[mf] = *(const bf16x8*)&lds[cb + 8192 + aoff[mf]];
#pragma unroll
        for (int nf = 0; nf < 4; ++nf) bfr[nf] = *(const bf16x8*)&lds[cb + 20480 + boff[nf]];
        if (pf) STAGE_U(nA + 8192, pb + 8192);
        __builtin_amdgcn_s_barrier();
        __builtin_amdgcn_s_setprio(1);
        MFMA16(acc, af, bfr);
        __builtin_amdgcn_s_setprio(0);
        VMCNT_END(2);
        __builtin_amdgcn_s_barrier();

        cur ^= 1;
    }

#pragma unroll
    for (int mf = 0; mf < 4; ++mf)
#pragma unroll
        for (int nf = 0; nf < 4; ++nf)
#pragma unroll
            for (int i = 0; i < 4; ++i) {
                int m = mblk * 256 + wr * 64 + mf * 16 + g4 * 4 + i;
                int n = nblk * 128 + wc * 64 + nf * 16 + rr;
                Out[(long)m * HDIM + n] = acc[mf][nf][i];
            }
}

// ================= host =================
extern "C" void kernel_launch(void* const* d_in, const int* in_sizes, int n_in,
                              void* d_out, int out_size, void* d_ws, size_t ws_size,
                              hipStream_t stream) {
    const float* x     = (const float*)d_in[0];
    const float* Wgu_l = (const float*)d_in[3];
    const float* Wd_l  = (const float*)d_in[4];
    const float* Wgu_v = (const float*)d_in[5];
    const float* Wd_v  = (const float*)d_in[6];
    float* out         = (float*)d_out;

    const size_t XP_B  = (size_t)8 * KT1 * 32768;        //  16.8 MB
    const size_t HP_B  = (size_t)8 * KT2 * 32768;        //  45.1 MB (one expert)
    const size_t WP_B  = (size_t)NB1 * KT1 * 32768;      // 180.4 MB
    const size_t NEED1 = XP_B + 2 * HP_B + WP_B;         // 287.4 MB

    if (ws_size >= NEED1) {
        ushort_t* XP = (ushort_t*)d_ws;
        ushort_t* HP = XP + XP_B / 2;
        ushort_t* WP = HP + HP_B;
        for (int e = 0; e < 2; ++e) {
            const float* xe = x + (long)e * MTOK * HDIM;
            conv_x  <<<dim3(16 * KT1),      dim3(256), 0, stream>>>(xe, XP);
            conv_wgu<<<dim3(NB1 * KT1 * 2), dim3(256), 0, stream>>>(e ? Wgu_v : Wgu_l, WP);
            gu14_kernel<<<dim3(8 * NB1),    dim3(512), 0, stream>>>(XP, WP, HP + (size_t)e * (HP_B / 2));
        }
        conv_wd2b<<<dim3(32 * KT2), dim3(256), 0, stream>>>(Wd_l, Wd_v, WP);
        down7_kernel<<<dim3(256), dim3(512), 0, stream>>>(HP, WP, out);
    } else {
        ushort_t* XP = (ushort_t*)d_ws;
        ushort_t* HP = XP + XP_B / 2;
        ushort_t* WP = HP + HP_B / 2;
        for (int e = 0; e < 2; ++e) {
            const float* xe = x + (long)e * MTOK * HDIM;
            float*       oe = out + (long)e * MTOK * HDIM;
            conv_x  <<<dim3(16 * KT1),      dim3(256), 0, stream>>>(xe, XP);
            conv_wgu<<<dim3(NB1 * KT1 * 2), dim3(256), 0, stream>>>(e ? Wgu_v : Wgu_l, WP);
            gu14_kernel<<<dim3(8 * NB1),    dim3(512), 0, stream>>>(XP, WP, HP);
            conv_wd <<<dim3(NB2 * KT2),     dim3(256), 0, stream>>>(e ? Wd_v : Wd_l, WP);
            down3_kernel<<<dim3(8 * NB2),   dim3(512), 0, stream>>>(HP, WP, oe);
        }
    }
}